// Round 8
// baseline (98.445 us; speedup 1.0000x reference)
//
#include <hip/hip_runtime.h>

// Fixed problem shapes
constexpr unsigned B  = 8, C = 32, H = 224, Wd = 224, ND = 8;
constexpr unsigned Ho = 222, Wo = 222;
constexpr unsigned PLANE  = Ho * Wo;      // 49284 floats per output plane
constexpr unsigned CHUNKS = PLANE / 4u;   // 12321 float4 chunks (exact)
constexpr unsigned DSTR   = C * PLANE;    // d-plane stride in floats
constexpr unsigned NWG    = (B * C * CHUNKS) / 256u;  // 12321 blocks
constexpr unsigned NXCD   = 8;
constexpr unsigned SWZ_Q  = NWG / NXCD;   // 1540
constexpr unsigned SWZ_R  = NWG % NXCD;   // 1

typedef float vf2 __attribute__((ext_vector_type(2)));
typedef float vf4 __attribute__((ext_vector_type(4)));

// One thread = one plane-linear float4 output chunk, computed for all 8 convs.
// XCD-chunked block swizzle (bijective, m204): consecutive logical blocks --
// which share input rows (3x vertical reuse, distance ~1 wave) and write
// adjacent 4KB output segments -- land on the SAME XCD, so reuse hits the
// local L2 and each XCD emits dense linear write fronts.
__global__ __launch_bounds__(256)
void dconv_kernel(const float* __restrict__ x,
                  const float* __restrict__ Wt,
                  const float* __restrict__ Bv,
                  float* __restrict__ out) {
    // ---- weights: wave-uniform -> one s_load set ----
    float w[ND][9];
    float bs[ND];
#pragma unroll
    for (int d = 0; d < (int)ND; ++d) {
#pragma unroll
        for (int q = 0; q < 9; ++q) w[d][q] = Wt[d * 9 + q];
        bs[d] = Bv[d];
    }

    // ---- bijective XCD-chunked swizzle ----
    const unsigned orig = blockIdx.x;
    const unsigned xcd  = orig % NXCD;
    const unsigned idx  = orig / NXCD;
    const unsigned wg   = (xcd < SWZ_R ? xcd * (SWZ_Q + 1u)
                                       : SWZ_R * (SWZ_Q + 1u) + (xcd - SWZ_R) * SWZ_Q)
                          + idx;

    const unsigned gid = wg * 256u + threadIdx.x;           // < 3,154,176
    const unsigned bc  = gid / CHUNKS;                      // (b*C + c), 0..255
    const unsigned k   = gid - bc * CHUNKS;                 // chunk in plane
    const unsigned b   = bc >> 5, c = bc & 31u;
    const unsigned fo  = k * 4u;                            // plane float offset
    const unsigned i   = fo / Wo;                           // first output row
    const unsigned jj  = fo - i * Wo;                       // first col (even)

    const float* xrow = x + ((unsigned long)bc * H + i) * Wd;
    const bool strad = (jj == 220u);   // chunk spans rows i and i+1

    float* const obase = out + (unsigned long)(b * (ND * C) + c) * PLANE + fo;

    // ---- Phase 1: input patch ----
    float p[3][6];
    float q2[3][4];
    if (!strad) {
#pragma unroll
        for (int r = 0; r < 3; ++r) {
            const float* rp = xrow + r * Wd + jj;
            const vf4 v4 = *reinterpret_cast<const vf4*>(rp);       // dense 1KB/wave
            const vf2 v2 = *reinterpret_cast<const vf2*>(rp + 4);
            p[r][0] = v4.x; p[r][1] = v4.y; p[r][2] = v4.z; p[r][3] = v4.w;
            p[r][4] = v2.x; p[r][5] = v2.y;
        }
    } else {
#pragma unroll
        for (int r = 0; r < 3; ++r) {
            const vf4 va = *reinterpret_cast<const vf4*>(xrow + r * Wd + 220);
            p[r][0] = va.x; p[r][1] = va.y; p[r][2] = va.z; p[r][3] = va.w;
            p[r][4] = 0.f;  p[r][5] = 0.f;
            const vf4 vb = *reinterpret_cast<const vf4*>(xrow + (r + 1) * Wd);
            q2[r][0] = vb.x; q2[r][1] = vb.y; q2[r][2] = vb.z; q2[r][3] = vb.w;
        }
    }

    // ---- Phase 2: all 8 convs into registers ----
    float a[ND][4];
    if (!strad) {
#pragma unroll
        for (int d = 0; d < (int)ND; ++d) {
            float a0 = bs[d], a1 = bs[d], a2 = bs[d], a3 = bs[d];
#pragma unroll
            for (int r = 0; r < 3; ++r) {
#pragma unroll
                for (int q = 0; q < 3; ++q) {
                    const float wv = w[d][r * 3 + q];
                    a0 = fmaf(wv, p[r][q + 0], a0);
                    a1 = fmaf(wv, p[r][q + 1], a1);
                    a2 = fmaf(wv, p[r][q + 2], a2);
                    a3 = fmaf(wv, p[r][q + 3], a3);
                }
            }
            a[d][0] = a0; a[d][1] = a1; a[d][2] = a2; a[d][3] = a3;
        }
    } else {
#pragma unroll
        for (int d = 0; d < (int)ND; ++d) {
            float a0 = bs[d], a1 = bs[d], a2 = bs[d], a3 = bs[d];
#pragma unroll
            for (int r = 0; r < 3; ++r) {
#pragma unroll
                for (int q = 0; q < 3; ++q) {
                    const float wv = w[d][r * 3 + q];
                    a0 = fmaf(wv, p[r][q + 0], a0);    // (i,   220)
                    a1 = fmaf(wv, p[r][q + 1], a1);    // (i,   221)
                    a2 = fmaf(wv, q2[r][q + 0], a2);   // (i+1, 0)
                    a3 = fmaf(wv, q2[r][q + 1], a3);   // (i+1, 1)
                }
            }
            a[d][0] = a0; a[d][1] = a1; a[d][2] = a2; a[d][3] = a3;
        }
    }

    // ---- Phase 3: 8 dense 16B stores back-to-back ----
#pragma unroll
    for (int d = 0; d < (int)ND; ++d) {
        vf4 s; s.x = a[d][0]; s.y = a[d][1]; s.z = a[d][2]; s.w = a[d][3];
        *reinterpret_cast<vf4*>(obase + (unsigned)d * DSTR) = s;
    }
}

extern "C" void kernel_launch(void* const* d_in, const int* in_sizes, int n_in,
                              void* d_out, int out_size, void* d_ws, size_t ws_size,
                              hipStream_t stream) {
    const float* x  = (const float*)d_in[0];
    const float* Wt = (const float*)d_in[1];   // [1, ND, 3, 3] flat
    const float* Bv = (const float*)d_in[2];   // [ND]
    float* out      = (float*)d_out;           // [B, ND*C, Ho, Wo]

    dconv_kernel<<<NWG, 256, 0, stream>>>(x, Wt, Bv, out);
}

// Round 9
// 75.512 us; speedup vs baseline: 1.3037x; 1.3037x over previous
//
#include <hip/hip_runtime.h>

// Fixed problem shapes
constexpr unsigned B  = 8, C = 32, H = 224, Wd = 224, ND = 8;
constexpr unsigned Ho = 222, Wo = 222;
constexpr unsigned PLANE  = Ho * Wo;      // 49284 floats per output plane
constexpr unsigned CHUNKS = PLANE / 4u;   // 12321 float4 chunks (exact)
constexpr unsigned DSTR   = C * PLANE;    // d-plane stride in floats

typedef float vf2 __attribute__((ext_vector_type(2)));
typedef float vf4 __attribute__((ext_vector_type(4)));

// One thread = one plane-linear float4 output chunk, computed for all 8 convs.
// Default (non-swizzled) block order: R7 showed XCD-chunking regresses here
// (input is L3-resident; swizzle only skews write-channel balance).
// Stores are nontemporal: every wave store covers 16 full 64B lines, and the
// output is write-once/never-read, so bypassing L2 write-allocate keeps L2
// for the input's 3x vertical reuse.
__global__ __launch_bounds__(256)
void dconv_kernel(const float* __restrict__ x,
                  const float* __restrict__ Wt,
                  const float* __restrict__ Bv,
                  float* __restrict__ out) {
    // ---- weights: wave-uniform -> one s_load set ----
    float w[ND][9];
    float bs[ND];
#pragma unroll
    for (int d = 0; d < (int)ND; ++d) {
#pragma unroll
        for (int q = 0; q < 9; ++q) w[d][q] = Wt[d * 9 + q];
        bs[d] = Bv[d];
    }

    const unsigned gid = blockIdx.x * 256u + threadIdx.x;   // < 3,154,176
    const unsigned bc  = gid / CHUNKS;                      // (b*C + c), 0..255
    const unsigned k   = gid - bc * CHUNKS;                 // chunk in plane
    const unsigned b   = bc >> 5, c = bc & 31u;
    const unsigned fo  = k * 4u;                            // plane float offset
    const unsigned i   = fo / Wo;                           // first output row
    const unsigned jj  = fo - i * Wo;                       // first col (even)

    const float* xrow = x + ((unsigned long)bc * H + i) * Wd;
    const bool strad = (jj == 220u);   // chunk spans rows i and i+1

    float* const obase = out + (unsigned long)(b * (ND * C) + c) * PLANE + fo;

    // ---- Phase 1: input patch ----
    float p[3][6];
    float q2[3][4];
    if (!strad) {
#pragma unroll
        for (int r = 0; r < 3; ++r) {
            const float* rp = xrow + r * Wd + jj;
            const vf4 v4 = *reinterpret_cast<const vf4*>(rp);       // dense 1KB/wave
            const vf2 v2 = *reinterpret_cast<const vf2*>(rp + 4);
            p[r][0] = v4.x; p[r][1] = v4.y; p[r][2] = v4.z; p[r][3] = v4.w;
            p[r][4] = v2.x; p[r][5] = v2.y;
        }
    } else {
#pragma unroll
        for (int r = 0; r < 3; ++r) {
            const vf4 va = *reinterpret_cast<const vf4*>(xrow + r * Wd + 220);
            p[r][0] = va.x; p[r][1] = va.y; p[r][2] = va.z; p[r][3] = va.w;
            p[r][4] = 0.f;  p[r][5] = 0.f;
            const vf4 vb = *reinterpret_cast<const vf4*>(xrow + (r + 1) * Wd);
            q2[r][0] = vb.x; q2[r][1] = vb.y; q2[r][2] = vb.z; q2[r][3] = vb.w;
        }
    }

    // ---- Phase 2: all 8 convs into registers ----
    float a[ND][4];
    if (!strad) {
#pragma unroll
        for (int d = 0; d < (int)ND; ++d) {
            float a0 = bs[d], a1 = bs[d], a2 = bs[d], a3 = bs[d];
#pragma unroll
            for (int r = 0; r < 3; ++r) {
#pragma unroll
                for (int q = 0; q < 3; ++q) {
                    const float wv = w[d][r * 3 + q];
                    a0 = fmaf(wv, p[r][q + 0], a0);
                    a1 = fmaf(wv, p[r][q + 1], a1);
                    a2 = fmaf(wv, p[r][q + 2], a2);
                    a3 = fmaf(wv, p[r][q + 3], a3);
                }
            }
            a[d][0] = a0; a[d][1] = a1; a[d][2] = a2; a[d][3] = a3;
        }
    } else {
#pragma unroll
        for (int d = 0; d < (int)ND; ++d) {
            float a0 = bs[d], a1 = bs[d], a2 = bs[d], a3 = bs[d];
#pragma unroll
            for (int r = 0; r < 3; ++r) {
#pragma unroll
                for (int q = 0; q < 3; ++q) {
                    const float wv = w[d][r * 3 + q];
                    a0 = fmaf(wv, p[r][q + 0], a0);    // (i,   220)
                    a1 = fmaf(wv, p[r][q + 1], a1);    // (i,   221)
                    a2 = fmaf(wv, q2[r][q + 0], a2);   // (i+1, 0)
                    a3 = fmaf(wv, q2[r][q + 1], a3);   // (i+1, 1)
                }
            }
            a[d][0] = a0; a[d][1] = a1; a[d][2] = a2; a[d][3] = a3;
        }
    }

    // ---- Phase 3: 8 dense 16B nontemporal stores back-to-back ----
#pragma unroll
    for (int d = 0; d < (int)ND; ++d) {
        vf4 s; s.x = a[d][0]; s.y = a[d][1]; s.z = a[d][2]; s.w = a[d][3];
        __builtin_nontemporal_store(s, reinterpret_cast<vf4*>(obase + (unsigned)d * DSTR));
    }
}

extern "C" void kernel_launch(void* const* d_in, const int* in_sizes, int n_in,
                              void* d_out, int out_size, void* d_ws, size_t ws_size,
                              hipStream_t stream) {
    const float* x  = (const float*)d_in[0];
    const float* Wt = (const float*)d_in[1];   // [1, ND, 3, 3] flat
    const float* Bv = (const float*)d_in[2];   // [ND]
    float* out      = (float*)d_out;           // [B, ND*C, Ho, Wo]

    const unsigned total  = B * C * CHUNKS;    // 3,154,176 threads
    const unsigned blocks = total / 256u;      // 12,321 exact
    dconv_kernel<<<blocks, 256, 0, stream>>>(x, Wt, Bv, out);
}